// Round 13
// baseline (159.413 us; speedup 1.0000x reference)
//
#include <hip/hip_runtime.h>

// VanillaVectorQuantizer: N=131072 pos (B=32,H=64,W=64), D=64, K=512.
// enc [B,D,H,W]: (b,d,p) at b*D*HW + d*HW + p.
//
// MFMA screen + rigorously-bounded exact rescore:
//  1. approx dist via mfma_f32_16x16x32_bf16 (RN-bf16 inputs, fp32 acc)
//  2. B = 0.025*sqrt(sqx*maxsqe)+1e-3 >= |approx-chain| (true bound
//     2^-6*||x||*||e||, 2.3x slack). Candidates: approx <= approxmin+2B.
//     Excluded k: exact_k >= approx_k - B > approxmin + B >= exact(argmin~)
//     -> strictly worse -> true argmin AND all exact ties are candidates.
//  3. exact rescore = bitwise numpy chain (verified r2-r12, absmax==0):
//     M: ascending-d fp32 FMA chain; sq_x: pairwise_sum(8 acc, mul+add);
//     sq_e: sequential mul+add; dist: fl(fl(sqx-fl(2M))+sqe);
//     u64 pack (distbits<<32|k) min == first-index tie-break (dist>0).
//     Overflow (>48 cand): full-512 exact rescan for that row (airtight).
// MFMA layouts: C/D col=lane&15,row=4*(lane>>4)+j [m89-verified];
// A[m][k]: m=lane&15, k=8*(lane>>4)+j; B[k][n]: n=lane&15, k=8*(lane>>4)+j.

#pragma clang fp contract(off)

#define D 64
#define Kc 512
#define HW 4096
#define Np 131072

typedef __attribute__((ext_vector_type(8))) short bf16x8;
typedef __attribute__((ext_vector_type(4))) float f32x4;

static __device__ __forceinline__ unsigned short f2bf(float f) {
    unsigned u = __float_as_uint(f);
    unsigned r = (u + 0x7fffu + ((u >> 16) & 1u)) >> 16;  // RN-even
    return (unsigned short)r;
}

// Prep: exact sqe chain, max(sqe), cbT bf16 [512][64] (k-major for B-frags).
__global__ __launch_bounds__(512) void vq_prep(
    const float* __restrict__ cb, float* __restrict__ sqe,
    float* __restrict__ maxsqe, unsigned short* __restrict__ cbT) {
    __shared__ float red[512];
    const int k = threadIdx.x;
    float s;
    unsigned pk[32];
    {
        const float v0 = cb[k], v1 = cb[Kc + k];
        s = v0 * v0;                       // d=0 (rounded square)
        const float sq1 = v1 * v1;
        s = s + sq1;                       // d=1 (rounded add)
        pk[0] = (unsigned)f2bf(v0) | ((unsigned)f2bf(v1) << 16);
    }
#pragma unroll
    for (int i = 1; i < 32; ++i) {
        const float v0 = cb[(2 * i) * Kc + k], v1 = cb[(2 * i + 1) * Kc + k];
        const float sq0 = v0 * v0;
        s = s + sq0;
        const float sq1 = v1 * v1;
        s = s + sq1;
        pk[i] = (unsigned)f2bf(v0) | ((unsigned)f2bf(v1) << 16);
    }
    sqe[k] = s;
    unsigned* crow = (unsigned*)(cbT + k * 64);
#pragma unroll
    for (int i = 0; i < 32; ++i) crow[i] = pk[i];
    red[k] = s;
    __syncthreads();
    for (int off = 256; off > 0; off >>= 1) {
        if (k < off) red[k] = fmaxf(red[k], red[k + off]);
        __syncthreads();
    }
    if (k == 0) maxsqe[0] = red[0];
}

__global__ __launch_bounds__(512) void vq_mfma_kernel(
    const float* __restrict__ enc, const float* __restrict__ cb,
    const float* __restrict__ sqe, const float* __restrict__ maxsqe_p,
    const unsigned short* __restrict__ cbT, float* __restrict__ out) {
    __shared__ unsigned short xbf[64 * 72];       // bf16 x, [pos][d], pad 72
    __shared__ float xf[64 * 68];                 // fp32 x, [pos][d], pad 68
    __shared__ float sqx[64];
    __shared__ float prb[64 * 8];
    __shared__ unsigned long long wmin[8 * 64];   // per-wave row mins
    __shared__ float thr[64];
    __shared__ unsigned cnt[64];
    __shared__ unsigned short list[64 * 48];
    __shared__ unsigned long long rmin[64 * 8];
    __shared__ int wk[64];

    const int tid = threadIdx.x;
    const int lane = tid & 63;
    const int wid = tid >> 6;          // 0..7 -> k in [64w, 64w+64)
    const int p0 = blockIdx.x * 64;    // 64 | 4096: block within one b
    const int b = p0 >> 12;
    const int r0 = p0 & (HW - 1);
    const float* eb = enc + (size_t)b * (D * HW) + r0;

    // Stage x: thread (d=tid>>3, pg=tid&7) reads 8 consecutive positions.
    {
        const int d = tid >> 3, pg = tid & 7;
        const float* src = eb + (size_t)d * HW + pg * 8;
        const float4 a = *reinterpret_cast<const float4*>(src);
        const float4 c = *reinterpret_cast<const float4*>(src + 4);
        const float vv[8] = {a.x, a.y, a.z, a.w, c.x, c.y, c.z, c.w};
#pragma unroll
        for (int i = 0; i < 8; ++i) {
            const int p = pg * 8 + i;
            xf[p * 68 + d] = vv[i];
            xbf[p * 72 + d] = f2bf(vv[i]);
        }
    }
    if (tid < 64) cnt[tid] = 0;
    wmin[tid] = ~0ULL;
    __syncthreads();

    // sq_x: exact numpy pairwise_sum. 8 threads per pos compute pr[j].
    {
        const int p = tid >> 3, j = tid & 7;
        float x0 = xf[p * 68 + j];
        float pr = x0 * x0;
#pragma unroll
        for (int i = 1; i < 8; ++i) {
            const float x = xf[p * 68 + 8 * i + j];
            const float sq = x * x;
            pr = pr + sq;
        }
        prb[p * 8 + j] = pr;
    }
    __syncthreads();
    if (tid < 64) {
        const float* q = &prb[tid * 8];
        sqx[tid] = ((q[0] + q[1]) + (q[2] + q[3])) +
                   ((q[4] + q[5]) + (q[6] + q[7]));
    }

    // MFMA: wave w covers k [64w,64w+64): 4 pos-tiles x 4 k-tiles x 2 Ksteps.
    f32x4 acc[4][4] = {};
    const int kb = wid * 64;
#pragma unroll
    for (int s = 0; s < 2; ++s) {
        bf16x8 A[4];
#pragma unroll
        for (int pt = 0; pt < 4; ++pt)
            A[pt] = *reinterpret_cast<const bf16x8*>(
                &xbf[(pt * 16 + (lane & 15)) * 72 + s * 32 + 8 * (lane >> 4)]);
#pragma unroll
        for (int kt = 0; kt < 4; ++kt) {
            const int kg = kb + kt * 16 + (lane & 15);
            const bf16x8 Bf = *reinterpret_cast<const bf16x8*>(
                &cbT[kg * 64 + s * 32 + 8 * (lane >> 4)]);
#pragma unroll
            for (int pt = 0; pt < 4; ++pt)
                acc[pt][kt] = __builtin_amdgcn_mfma_f32_16x16x32_bf16(
                    A[pt], Bf, acc[pt][kt], 0, 0, 0);
        }
    }
    __syncthreads();  // sqx ready; MFMAs done

    float se4[4];
#pragma unroll
    for (int kt = 0; kt < 4; ++kt) se4[kt] = sqe[kb + kt * 16 + (lane & 15)];

    // Per-row approx min over this wave's 64 ks (C/D: col=lane&15,
    // row=4*(lane>>4)+j within tile).
#pragma unroll
    for (int pt = 0; pt < 4; ++pt) {
        unsigned long long m[4] = {~0ULL, ~0ULL, ~0ULL, ~0ULL};
#pragma unroll
        for (int kt = 0; kt < 4; ++kt) {
            const unsigned kg = kb + kt * 16 + (lane & 15);
#pragma unroll
            for (int j = 0; j < 4; ++j) {
                const int pl = pt * 16 + 4 * (lane >> 4) + j;
                const float dd = (sqx[pl] - 2.0f * acc[pt][kt][j]) + se4[kt];
                const unsigned long long pk =
                    ((unsigned long long)__float_as_uint(dd) << 32) | kg;
                if (pk < m[j]) m[j] = pk;
            }
        }
#pragma unroll
        for (int j = 0; j < 4; ++j) {
#pragma unroll
            for (int w = 1; w < 16; w <<= 1) {
                const unsigned long long o = __shfl_xor(m[j], w, 16);
                if (o < m[j]) m[j] = o;
            }
            if ((lane & 15) == 0)
                wmin[wid * 64 + pt * 16 + 4 * (lane >> 4) + j] = m[j];
        }
    }
    __syncthreads();
    if (tid < 64) {
        unsigned long long mm = wmin[tid];
#pragma unroll
        for (int w = 1; w < 8; ++w) {
            const unsigned long long o = wmin[w * 64 + tid];
            if (o < mm) mm = o;
        }
        const float dmin = __uint_as_float((unsigned)(mm >> 32));
        const float Bnd = 0.025f * sqrtf(sqx[tid] * maxsqe_p[0]) + 1e-3f;
        thr[tid] = dmin + 2.0f * Bnd;
    }
    __syncthreads();

    // Candidate scan: recompute approx dists from live acc.
#pragma unroll
    for (int pt = 0; pt < 4; ++pt) {
#pragma unroll
        for (int kt = 0; kt < 4; ++kt) {
            const unsigned kg = kb + kt * 16 + (lane & 15);
#pragma unroll
            for (int j = 0; j < 4; ++j) {
                const int pl = pt * 16 + 4 * (lane >> 4) + j;
                const float dd = (sqx[pl] - 2.0f * acc[pt][kt][j]) + se4[kt];
                if (dd <= thr[pl]) {
                    const unsigned idx = atomicAdd(&cnt[pl], 1u);
                    if (idx < 48) list[pl * 48 + idx] = (unsigned short)kg;
                }
            }
        }
    }
    __syncthreads();

    // Exact rescore (bitwise numpy chain) of candidates; 8 threads per pos.
    {
        const int p = tid >> 3, sub = tid & 7;
        const unsigned n = cnt[p];
        const float sx = sqx[p];
        unsigned long long m = ~0ULL;
        if (n <= 48) {
            for (unsigned c = sub; c < n; c += 8) {
                const int k = list[p * 48 + c];
                float M = 0.f;
#pragma unroll 8
                for (int d = 0; d < D; ++d)
                    M = fmaf(xf[p * 68 + d], cb[d * Kc + k], M);
                const float m2 = 2.0f * M;
                const float tmp = sx - m2;
                const float dd = tmp + sqe[k];
                const unsigned long long pk =
                    ((unsigned long long)__float_as_uint(dd) << 32) |
                    (unsigned)k;
                if (pk < m) m = pk;
            }
        } else {  // overflow fallback: exact-rescan ALL ks (rare, airtight)
            for (unsigned k = sub; k < Kc; k += 8) {
                float M = 0.f;
#pragma unroll 8
                for (int d = 0; d < D; ++d)
                    M = fmaf(xf[p * 68 + d], cb[d * Kc + k], M);
                const float m2 = 2.0f * M;
                const float tmp = sx - m2;
                const float dd = tmp + sqe[k];
                const unsigned long long pk =
                    ((unsigned long long)__float_as_uint(dd) << 32) | k;
                if (pk < m) m = pk;
            }
        }
        rmin[p * 8 + sub] = m;
    }
    __syncthreads();
    if (tid < 64) {
        unsigned long long m = rmin[tid * 8];
#pragma unroll
        for (int s = 1; s < 8; ++s) {
            const unsigned long long o = rmin[tid * 8 + s];
            if (o < m) m = o;
        }
        wk[tid] = (int)(m & 0xffffffffu);
    }
    __syncthreads();

    // Output: thread (d, pg) writes 8 consecutive positions (32B stores).
    {
        const int d = tid >> 3, pg = tid & 7;
        float o[8];
#pragma unroll
        for (int i = 0; i < 8; ++i) o[i] = cb[d * Kc + wk[pg * 8 + i]];
        float* dst = out + (size_t)b * (D * HW) + r0 + (size_t)d * HW + pg * 8;
        float4 v0 = {o[0], o[1], o[2], o[3]};
        float4 v1 = {o[4], o[5], o[6], o[7]};
        *reinterpret_cast<float4*>(dst) = v0;
        *reinterpret_cast<float4*>(dst + 4) = v1;
    }
}

extern "C" void kernel_launch(void* const* d_in, const int* in_sizes, int n_in,
                              void* d_out, int out_size, void* d_ws, size_t ws_size,
                              hipStream_t stream) {
    const float* enc = (const float*)d_in[0];  // [32,64,64,64]
    const float* cb  = (const float*)d_in[1];  // [64,512]
    float* out = (float*)d_out;
    float* sqe = (float*)d_ws;                           // 512 f32 @ 0
    float* maxsqe = (float*)((char*)d_ws + 2048);        // 1 f32
    unsigned short* cbT = (unsigned short*)((char*)d_ws + 4096);  // 64 KB

    vq_prep<<<1, 512, 0, stream>>>(cb, sqe, maxsqe, cbT);
    vq_mfma_kernel<<<Np / 64, 512, 0, stream>>>(enc, cb, sqe, maxsqe, cbT, out);
}

// Round 14
// 78.383 us; speedup vs baseline: 2.0338x; 2.0338x over previous
//
#include <hip/hip_runtime.h>

// VanillaVectorQuantizer: N=131072 pos (B=32,H=64,W=64), D=64, K=512.
// enc [B,D,H,W]: (b,d,p) at b*D*HW + d*HW + p.
//
// Architecture (r13-proven, absmax==0): MFMA screen + bounded exact rescore.
//  screen: dd'_k = fl(sqe_k - 2*acc_k), acc = bf16 MFMA (products exact in
//    fp32; |acc-M| <= 2^-8*1.01*||x||*||e|| + ~3e-7).
//  bound:  B' = 0.012*sqrt(sqx*maxsqe) + 3e-4  (>= 1.5x rigorous bound on
//    |exact_chain - (dd' + sqx)|; sqx const per row -> order preserved).
//  capture: cand = {k: dd' <= dmin' + 2B'}; excluded k has exact_k strictly
//    > exact(ddmin-k) -> true argmin AND all exact ties are candidates.
//  rescore: EXACT numpy chain (bitwise, r2-r13): M ascending-d fp32 FMA;
//    sq_x pairwise_sum tree; dist fl(fl(sqx-fl(2M))+sqe); u64 (distbits,k)
//    atomicMin == first-index tie-break. Overflow(>16) -> full 512 rescan.
// MFMA frags (r13-verified end-to-end): A = xbf[(row)*72 + s*32 + 8*hi];
// B = cbT[kg*64 + s*32 + 8*hi], kg = kbase + kt*16 + m; C/D row=4*hi+j,
// col=m, with m=lane&15, hi=lane>>4.
//
// v2 vs r13 (159us, MfmaUtil 2%, 9 phases, 64pos/block): 256 pos/block,
// 4 barriers, wave owns k-range so B-frags+sqe load ONCE per pass (32 VGPR),
// sqx half-trees in registers during staging (no xf LDS), b64-packed bf16
// staging writes, rescore x from global (L2-hot).

#pragma clang fp contract(off)

#define D 64
#define Kc 512
#define HW 4096
#define Np 131072
#define POSB 256
#define NW 8
#define CAP 16

typedef __attribute__((ext_vector_type(8))) short bf16x8;
typedef __attribute__((ext_vector_type(4))) float f32x4;

static __device__ __forceinline__ unsigned short f2bf(float f) {
    unsigned u = __float_as_uint(f);
    unsigned r = (u + 0x7fffu + ((u >> 16) & 1u)) >> 16;  // RN-even
    return (unsigned short)r;
}

// Prep: exact sqe chain, max(sqe), cbT bf16 [512][64] (k-major).
__global__ __launch_bounds__(512) void vq_prep(
    const float* __restrict__ cb, float* __restrict__ sqe,
    float* __restrict__ maxsqe, unsigned short* __restrict__ cbT) {
    __shared__ float red[512];
    const int k = threadIdx.x;
    float s;
    unsigned pk[32];
    {
        const float v0 = cb[k], v1 = cb[Kc + k];
        s = v0 * v0;
        const float sq1 = v1 * v1;
        s = s + sq1;
        pk[0] = (unsigned)f2bf(v0) | ((unsigned)f2bf(v1) << 16);
    }
#pragma unroll
    for (int i = 1; i < 32; ++i) {
        const float v0 = cb[(2 * i) * Kc + k], v1 = cb[(2 * i + 1) * Kc + k];
        const float sq0 = v0 * v0;
        s = s + sq0;
        const float sq1 = v1 * v1;
        s = s + sq1;
        pk[i] = (unsigned)f2bf(v0) | ((unsigned)f2bf(v1) << 16);
    }
    sqe[k] = s;
    unsigned* crow = (unsigned*)(cbT + k * 64);
#pragma unroll
    for (int i = 0; i < 32; ++i) crow[i] = pk[i];
    red[k] = s;
    __syncthreads();
    for (int off = 256; off > 0; off >>= 1) {
        if (k < off) red[k] = fmaxf(red[k], red[k + off]);
        __syncthreads();
    }
    if (k == 0) maxsqe[0] = red[0];
}

__global__ __launch_bounds__(512) void vq_mfma2(
    const float* __restrict__ enc, const float* __restrict__ cb,
    const float* __restrict__ sqe, const float* __restrict__ maxsqe_p,
    const unsigned short* __restrict__ cbT, float* __restrict__ out) {
    __shared__ unsigned short xbf[POSB * 72];    // 36864 B, stride 144B
    __shared__ float sqxp[2 * POSB];             //  2048 B (half-trees)
    __shared__ float wmin[NW * POSB];            //  8192 B
    __shared__ float thr[POSB];                  //  1024 B
    __shared__ unsigned cnt[POSB];               //  1024 B
    __shared__ unsigned short list[POSB * CAP];  //  8192 B
    __shared__ unsigned long long rmin[POSB];    //  2048 B  (~59 KB total)

    const int tid = threadIdx.x;
    const int w = tid >> 6;
    const int lane = tid & 63;
    const int m = lane & 15, hi = lane >> 4;
    const int p0 = blockIdx.x * POSB;  // 256 | 4096: block within one b
    const int b = p0 >> 12;
    const int r0 = p0 & (HW - 1);
    const float* eb = enc + (size_t)b * (D * HW) + r0;

    // ---- Stage: thread owns pos p, half h (d = 8i+4h+{0..3}) ----
    // Computes its sq_x half-tree IN REGISTERS (exact numpy pairwise order),
    // packs bf16 pairs as one b64 LDS write per i.
    {
        const int p = tid & 255, h = tid >> 8;
        const float* ebp = eb + p;
        float pr0, pr1, pr2, pr3;
        {
            const int d = 4 * h;
            const float v0 = ebp[(d + 0) * HW], v1 = ebp[(d + 1) * HW];
            const float v2 = ebp[(d + 2) * HW], v3 = ebp[(d + 3) * HW];
            pr0 = v0 * v0; pr1 = v1 * v1; pr2 = v2 * v2; pr3 = v3 * v3;
            const unsigned long long pk =
                (unsigned long long)((unsigned)f2bf(v0) |
                                     ((unsigned)f2bf(v1) << 16)) |
                ((unsigned long long)((unsigned)f2bf(v2) |
                                      ((unsigned)f2bf(v3) << 16)) << 32);
            *reinterpret_cast<unsigned long long*>(
                reinterpret_cast<char*>(xbf) + p * 144 + 8 * h) = pk;
        }
#pragma unroll
        for (int i = 1; i < 8; ++i) {
            const int d = 8 * i + 4 * h;
            const float v0 = ebp[(d + 0) * HW], v1 = ebp[(d + 1) * HW];
            const float v2 = ebp[(d + 2) * HW], v3 = ebp[(d + 3) * HW];
            const float s0 = v0 * v0; pr0 = pr0 + s0;  // rounded sq, rounded add
            const float s1 = v1 * v1; pr1 = pr1 + s1;
            const float s2 = v2 * v2; pr2 = pr2 + s2;
            const float s3 = v3 * v3; pr3 = pr3 + s3;
            const unsigned long long pk =
                (unsigned long long)((unsigned)f2bf(v0) |
                                     ((unsigned)f2bf(v1) << 16)) |
                ((unsigned long long)((unsigned)f2bf(v2) |
                                      ((unsigned)f2bf(v3) << 16)) << 32);
            *reinterpret_cast<unsigned long long*>(
                reinterpret_cast<char*>(xbf) + p * 144 + 16 * i + 8 * h) = pk;
        }
        // h=0: (pr0+pr1)+(pr2+pr3); h=1: (pr4+pr5)+(pr6+pr7)  [exact tree]
        sqxp[h * 256 + p] = (pr0 + pr1) + (pr2 + pr3);
    }
    if (tid < POSB) { cnt[tid] = 0; rmin[tid] = ~0ULL; }
    __syncthreads();  // bar1

    // ---- B-fragments + sqe for this wave's k-range (live both passes) ----
    bf16x8 Bf[4][2];
    float se[4];
#pragma unroll
    for (int kt = 0; kt < 4; ++kt) {
        const int kg = 64 * w + kt * 16 + m;
#pragma unroll
        for (int s = 0; s < 2; ++s)
            Bf[kt][s] = *reinterpret_cast<const bf16x8*>(
                &cbT[kg * 64 + s * 32 + 8 * hi]);
        se[kt] = sqe[kg];
    }

    // ---- Pass 1: row-min of dd' over this wave's 64 ks ----
#pragma unroll 2
    for (int pt = 0; pt < 16; ++pt) {
        const int rowb = pt * 16;
        f32x4 acc[4] = {};
        {
            const bf16x8 A0 = *reinterpret_cast<const bf16x8*>(
                &xbf[(rowb + m) * 72 + 8 * hi]);
#pragma unroll
            for (int kt = 0; kt < 4; ++kt)
                acc[kt] = __builtin_amdgcn_mfma_f32_16x16x32_bf16(
                    A0, Bf[kt][0], acc[kt], 0, 0, 0);
            const bf16x8 A1 = *reinterpret_cast<const bf16x8*>(
                &xbf[(rowb + m) * 72 + 32 + 8 * hi]);
#pragma unroll
            for (int kt = 0; kt < 4; ++kt)
                acc[kt] = __builtin_amdgcn_mfma_f32_16x16x32_bf16(
                    A1, Bf[kt][1], acc[kt], 0, 0, 0);
        }
        float mn0 = 3.4e38f, mn1 = 3.4e38f, mn2 = 3.4e38f, mn3 = 3.4e38f;
#pragma unroll
        for (int kt = 0; kt < 4; ++kt) {
            mn0 = fminf(mn0, fmaf(-2.f, acc[kt][0], se[kt]));
            mn1 = fminf(mn1, fmaf(-2.f, acc[kt][1], se[kt]));
            mn2 = fminf(mn2, fmaf(-2.f, acc[kt][2], se[kt]));
            mn3 = fminf(mn3, fmaf(-2.f, acc[kt][3], se[kt]));
        }
#pragma unroll
        for (int st = 1; st < 16; st <<= 1) {
            mn0 = fminf(mn0, __shfl_xor(mn0, st, 16));
            mn1 = fminf(mn1, __shfl_xor(mn1, st, 16));
            mn2 = fminf(mn2, __shfl_xor(mn2, st, 16));
            mn3 = fminf(mn3, __shfl_xor(mn3, st, 16));
        }
        if (m == 0) {
            float4 wv = {mn0, mn1, mn2, mn3};
            *reinterpret_cast<float4*>(&wmin[w * POSB + rowb + 4 * hi]) = wv;
        }
    }
    __syncthreads();  // bar2

    // ---- Threshold per row ----
    if (tid < POSB) {
        float mn = wmin[tid];
#pragma unroll
        for (int i = 1; i < NW; ++i) mn = fminf(mn, wmin[i * POSB + tid]);
        const float sx = sqxp[tid] + sqxp[256 + tid];
        const float Bnd = 0.012f * sqrtf(sx * maxsqe_p[0]) + 3e-4f;
        thr[tid] = mn + 2.0f * Bnd;
    }
    __syncthreads();  // bar3

    // ---- Pass 2: collect candidates ----
#pragma unroll 2
    for (int pt = 0; pt < 16; ++pt) {
        const int rowb = pt * 16;
        f32x4 acc[4] = {};
        {
            const bf16x8 A0 = *reinterpret_cast<const bf16x8*>(
                &xbf[(rowb + m) * 72 + 8 * hi]);
#pragma unroll
            for (int kt = 0; kt < 4; ++kt)
                acc[kt] = __builtin_amdgcn_mfma_f32_16x16x32_bf16(
                    A0, Bf[kt][0], acc[kt], 0, 0, 0);
            const bf16x8 A1 = *reinterpret_cast<const bf16x8*>(
                &xbf[(rowb + m) * 72 + 32 + 8 * hi]);
#pragma unroll
            for (int kt = 0; kt < 4; ++kt)
                acc[kt] = __builtin_amdgcn_mfma_f32_16x16x32_bf16(
                    A1, Bf[kt][1], acc[kt], 0, 0, 0);
        }
        const float4 tr =
            *reinterpret_cast<const float4*>(&thr[rowb + 4 * hi]);
#pragma unroll
        for (int kt = 0; kt < 4; ++kt) {
            const int kg = 64 * w + kt * 16 + m;
            const float dd0 = fmaf(-2.f, acc[kt][0], se[kt]);
            const float dd1 = fmaf(-2.f, acc[kt][1], se[kt]);
            const float dd2 = fmaf(-2.f, acc[kt][2], se[kt]);
            const float dd3 = fmaf(-2.f, acc[kt][3], se[kt]);
            if (dd0 <= tr.x) {
                const unsigned idx = atomicAdd(&cnt[rowb + 4 * hi + 0], 1u);
                if (idx < CAP) list[(rowb + 4 * hi + 0) * CAP + idx] = (unsigned short)kg;
            }
            if (dd1 <= tr.y) {
                const unsigned idx = atomicAdd(&cnt[rowb + 4 * hi + 1], 1u);
                if (idx < CAP) list[(rowb + 4 * hi + 1) * CAP + idx] = (unsigned short)kg;
            }
            if (dd2 <= tr.z) {
                const unsigned idx = atomicAdd(&cnt[rowb + 4 * hi + 2], 1u);
                if (idx < CAP) list[(rowb + 4 * hi + 2) * CAP + idx] = (unsigned short)kg;
            }
            if (dd3 <= tr.w) {
                const unsigned idx = atomicAdd(&cnt[rowb + 4 * hi + 3], 1u);
                if (idx < CAP) list[(rowb + 4 * hi + 3) * CAP + idx] = (unsigned short)kg;
            }
        }
    }
    __syncthreads();  // bar4

    // ---- Exact rescore (bitwise numpy chain); 2 threads per pos ----
    {
        const int p = tid >> 1, sub = tid & 1;
        const unsigned n = cnt[p];
        const float sx = sqxp[p] + sqxp[256 + p];
        unsigned long long mloc = ~0ULL;
        if (n <= CAP) {
            for (unsigned c = sub; c < n; c += 2) {
                const int k = list[p * CAP + c];
                float M = 0.f;
#pragma unroll 8
                for (int d = 0; d < D; ++d)
                    M = fmaf(eb[d * HW + p], cb[d * Kc + k], M);
                const float m2 = 2.0f * M;
                const float tmp = sx - m2;
                const float dd = tmp + sqe[k];
                const unsigned long long pk =
                    ((unsigned long long)__float_as_uint(dd) << 32) | (unsigned)k;
                if (pk < mloc) mloc = pk;
            }
        } else {  // overflow: full exact rescan (rare, airtight)
            for (unsigned k = sub; k < (unsigned)Kc; k += 2) {
                float M = 0.f;
#pragma unroll 8
                for (int d = 0; d < D; ++d)
                    M = fmaf(eb[d * HW + p], cb[d * Kc + k], M);
                const float m2 = 2.0f * M;
                const float tmp = sx - m2;
                const float dd = tmp + sqe[k];
                const unsigned long long pk =
                    ((unsigned long long)__float_as_uint(dd) << 32) | k;
                if (pk < mloc) mloc = pk;
            }
        }
        if (mloc != ~0ULL) atomicMin(&rmin[p], mloc);
    }
    __syncthreads();  // bar5

    // ---- Output: thread (d, pg) writes 8-pos float4 pairs, 4 reps ----
    {
        const int d = tid >> 3, pg = tid & 7;
        float* ob = out + (size_t)b * (D * HW) + r0 + (size_t)d * HW;
#pragma unroll
        for (int r = 0; r < 4; ++r) {
            const int pb = r * 64 + pg * 8;
            float o[8];
#pragma unroll
            for (int i = 0; i < 8; ++i) {
                const int k = (int)(rmin[pb + i] & 0xffffffffu);
                o[i] = cb[d * Kc + k];
            }
            float4 v0 = {o[0], o[1], o[2], o[3]};
            float4 v1 = {o[4], o[5], o[6], o[7]};
            *reinterpret_cast<float4*>(ob + pb) = v0;
            *reinterpret_cast<float4*>(ob + pb + 4) = v1;
        }
    }
}

extern "C" void kernel_launch(void* const* d_in, const int* in_sizes, int n_in,
                              void* d_out, int out_size, void* d_ws, size_t ws_size,
                              hipStream_t stream) {
    const float* enc = (const float*)d_in[0];  // [32,64,64,64]
    const float* cb  = (const float*)d_in[1];  // [64,512]
    float* out = (float*)d_out;
    float* sqe = (float*)d_ws;                           // 512 f32
    float* maxsqe = (float*)((char*)d_ws + 2048);        // 1 f32
    unsigned short* cbT = (unsigned short*)((char*)d_ws + 4096);  // 64 KB

    vq_prep<<<1, 512, 0, stream>>>(cb, sqe, maxsqe, cbT);
    vq_mfma2<<<Np / POSB, 512, 0, stream>>>(enc, cb, sqe, maxsqe, cbT, out);
}

// Round 15
// 74.232 us; speedup vs baseline: 2.1475x; 1.0559x over previous
//
#include <hip/hip_runtime.h>
#include <hip/hip_bf16.h>

// VanillaVectorQuantizer: N=131072 pos (B=32,H=64,W=64), D=64, K=512.
// enc [B,D,H,W]: (b,d,p) at b*D*HW + d*HW + p.
//
// Architecture (r13/r14-proven, absmax==0): MFMA screen + bounded exact
// rescore.
//  screen: dd'_k = fl(sqe_k - 2*acc_k), acc = bf16 MFMA (fp32 accum).
//  bound:  B' = 0.012*sqrt(sqx*maxsqe) + 3e-4 (~1.5x rigorous bound on
//    |exact_chain - (dd' + sqx)|; sqx const per row -> order preserved).
//  capture: cand = {k: dd' <= dmin' + 2B'}; excluded k strictly worse ->
//    true argmin AND all exact ties are candidates.
//  rescore: EXACT numpy chain (bitwise, r2-r14): M ascending-d fp32 FMA;
//    sq_x pairwise_sum tree; dist fl(fl(sqx-fl(2M))+sqe); u64 (distbits,k)
//    atomicMin == first-index tie-break. Overflow(>16) -> full 512 rescan.
// MFMA frags (r13/r14-verified): A = xbf[row*72 + s*32 + 8*hi];
// B = cbT[kg*64 + s*32 + 8*hi], kg = 64w + kt*16 + m; C/D row=4*hi+j,
// col=m (m=lane&15, hi=lane>>4).
//
// v3 vs r14 (78us, Occ 36%, LDS 59KB -> 2 blocks/CU, phase-serialization):
// POSB 128 -> LDS ~31KB -> 4 blocks/CU (cross-block phase overlap);
// staging remapped (p=tid>>2, h=tid&3): thread owns pairwise-tree node
// (pr[2h]+pr[2h+1]) -> bitwise tree, 2-way (not 8-way) LDS write banks;
// hardware RN bf16 cast replaces bit-manip f2bf.

#pragma clang fp contract(off)

#define D 64
#define Kc 512
#define HW 4096
#define Np 131072
#define POSB 128
#define NW 8
#define CAP 16

typedef __attribute__((ext_vector_type(8))) short bf16x8;
typedef __attribute__((ext_vector_type(4))) float f32x4;

static __device__ __forceinline__ unsigned short f2bf(float f) {
    __hip_bfloat16 h = __float2bfloat16(f);  // RN-even (bound covers it)
    return *reinterpret_cast<unsigned short*>(&h);
}

// Prep: exact sqe chain, max(sqe), cbT bf16 [512][64] (k-major).
__global__ __launch_bounds__(512) void vq_prep(
    const float* __restrict__ cb, float* __restrict__ sqe,
    float* __restrict__ maxsqe, unsigned short* __restrict__ cbT) {
    __shared__ float red[512];
    const int k = threadIdx.x;
    float s;
    unsigned pk[32];
    {
        const float v0 = cb[k], v1 = cb[Kc + k];
        s = v0 * v0;
        const float sq1 = v1 * v1;
        s = s + sq1;
        pk[0] = (unsigned)f2bf(v0) | ((unsigned)f2bf(v1) << 16);
    }
#pragma unroll
    for (int i = 1; i < 32; ++i) {
        const float v0 = cb[(2 * i) * Kc + k], v1 = cb[(2 * i + 1) * Kc + k];
        const float sq0 = v0 * v0;
        s = s + sq0;
        const float sq1 = v1 * v1;
        s = s + sq1;
        pk[i] = (unsigned)f2bf(v0) | ((unsigned)f2bf(v1) << 16);
    }
    sqe[k] = s;
    unsigned* crow = (unsigned*)(cbT + k * 64);
#pragma unroll
    for (int i = 0; i < 32; ++i) crow[i] = pk[i];
    red[k] = s;
    __syncthreads();
    for (int off = 256; off > 0; off >>= 1) {
        if (k < off) red[k] = fmaxf(red[k], red[k + off]);
        __syncthreads();
    }
    if (k == 0) maxsqe[0] = red[0];
}

__global__ __launch_bounds__(512) void vq_mfma3(
    const float* __restrict__ enc, const float* __restrict__ cb,
    const float* __restrict__ sqe, const float* __restrict__ maxsqe_p,
    const unsigned short* __restrict__ cbT, float* __restrict__ out) {
    __shared__ unsigned short xbf[POSB * 72];    // 18432 B, stride 144B
    __shared__ float sqxp[4 * POSB];             //  2048 B (tree nodes)
    __shared__ float wmin[NW * POSB];            //  4096 B
    __shared__ float thr[POSB];                  //   512 B
    __shared__ unsigned cnt[POSB];               //   512 B
    __shared__ unsigned short list[POSB * CAP];  //  4096 B
    __shared__ unsigned long long rmin[POSB];    //  1024 B (~30.7 KB total)

    const int tid = threadIdx.x;
    const int w = tid >> 6;
    const int lane = tid & 63;
    const int m = lane & 15, hi = lane >> 4;
    const int p0 = blockIdx.x * POSB;  // 128 | 4096: block within one b
    const int b = p0 >> 12;
    const int r0 = p0 & (HW - 1);
    const float* eb = enc + (size_t)b * (D * HW) + r0;

    // ---- Stage: thread owns (p = tid>>2, h = tid&3) -> stride-8 pairwise
    // accumulators pr[2h], pr[2h+1]; node (pr[2h]+pr[2h+1]) is bitwise the
    // numpy pairwise tree. bf16 pairs packed as one u32 LDS write per i
    // (banks: dword addr = 36p+4i+h -> lanes h0..3,p consec -> 2-way only).
    {
        const int p = tid >> 2, h = tid & 3;
        const float* ebp = eb + p;
        float pa, pb2;
        {
            const int d = 2 * h;
            const float v0 = ebp[(size_t)d * HW], v1 = ebp[(size_t)(d + 1) * HW];
            pa = v0 * v0;
            pb2 = v1 * v1;
            *reinterpret_cast<unsigned*>(
                reinterpret_cast<char*>(xbf) + p * 144 + 4 * h) =
                (unsigned)f2bf(v0) | ((unsigned)f2bf(v1) << 16);
        }
#pragma unroll
        for (int i = 1; i < 8; ++i) {
            const int d = 8 * i + 2 * h;
            const float v0 = ebp[(size_t)d * HW], v1 = ebp[(size_t)(d + 1) * HW];
            const float s0 = v0 * v0;  // rounded square
            pa = pa + s0;              // rounded add (stride-8 acc 2h)
            const float s1 = v1 * v1;
            pb2 = pb2 + s1;            // (stride-8 acc 2h+1)
            *reinterpret_cast<unsigned*>(
                reinterpret_cast<char*>(xbf) + p * 144 + 16 * i + 4 * h) =
                (unsigned)f2bf(v0) | ((unsigned)f2bf(v1) << 16);
        }
        sqxp[h * POSB + p] = pa + pb2;  // exact tree node
    }
    if (tid < POSB) { cnt[tid] = 0; rmin[tid] = ~0ULL; }
    __syncthreads();  // bar1

    // ---- B-fragments + sqe for this wave's k-range (live both passes) ----
    bf16x8 Bf[4][2];
    float se[4];
#pragma unroll
    for (int kt = 0; kt < 4; ++kt) {
        const int kg = 64 * w + kt * 16 + m;
#pragma unroll
        for (int s = 0; s < 2; ++s)
            Bf[kt][s] = *reinterpret_cast<const bf16x8*>(
                &cbT[kg * 64 + s * 32 + 8 * hi]);
        se[kt] = sqe[kg];
    }

    // ---- Pass 1: row-min of dd' over this wave's 64 ks ----
#pragma unroll 2
    for (int pt = 0; pt < POSB / 16; ++pt) {
        const int rowb = pt * 16;
        f32x4 acc[4] = {};
        {
            const bf16x8 A0 = *reinterpret_cast<const bf16x8*>(
                &xbf[(rowb + m) * 72 + 8 * hi]);
#pragma unroll
            for (int kt = 0; kt < 4; ++kt)
                acc[kt] = __builtin_amdgcn_mfma_f32_16x16x32_bf16(
                    A0, Bf[kt][0], acc[kt], 0, 0, 0);
            const bf16x8 A1 = *reinterpret_cast<const bf16x8*>(
                &xbf[(rowb + m) * 72 + 32 + 8 * hi]);
#pragma unroll
            for (int kt = 0; kt < 4; ++kt)
                acc[kt] = __builtin_amdgcn_mfma_f32_16x16x32_bf16(
                    A1, Bf[kt][1], acc[kt], 0, 0, 0);
        }
        float mn0 = 3.4e38f, mn1 = 3.4e38f, mn2 = 3.4e38f, mn3 = 3.4e38f;
#pragma unroll
        for (int kt = 0; kt < 4; ++kt) {
            mn0 = fminf(mn0, fmaf(-2.f, acc[kt][0], se[kt]));
            mn1 = fminf(mn1, fmaf(-2.f, acc[kt][1], se[kt]));
            mn2 = fminf(mn2, fmaf(-2.f, acc[kt][2], se[kt]));
            mn3 = fminf(mn3, fmaf(-2.f, acc[kt][3], se[kt]));
        }
#pragma unroll
        for (int st = 1; st < 16; st <<= 1) {
            mn0 = fminf(mn0, __shfl_xor(mn0, st, 16));
            mn1 = fminf(mn1, __shfl_xor(mn1, st, 16));
            mn2 = fminf(mn2, __shfl_xor(mn2, st, 16));
            mn3 = fminf(mn3, __shfl_xor(mn3, st, 16));
        }
        if (m == 0) {
            float4 wv = {mn0, mn1, mn2, mn3};
            *reinterpret_cast<float4*>(&wmin[w * POSB + rowb + 4 * hi]) = wv;
        }
    }
    __syncthreads();  // bar2

    // ---- Threshold per row ----
    if (tid < POSB) {
        float mn = wmin[tid];
#pragma unroll
        for (int i = 1; i < NW; ++i) mn = fminf(mn, wmin[i * POSB + tid]);
        const float sx = (sqxp[tid] + sqxp[POSB + tid]) +
                         (sqxp[2 * POSB + tid] + sqxp[3 * POSB + tid]);
        const float Bnd = 0.012f * sqrtf(sx * maxsqe_p[0]) + 3e-4f;
        thr[tid] = mn + 2.0f * Bnd;
    }
    __syncthreads();  // bar3

    // ---- Pass 2: collect candidates ----
#pragma unroll 2
    for (int pt = 0; pt < POSB / 16; ++pt) {
        const int rowb = pt * 16;
        f32x4 acc[4] = {};
        {
            const bf16x8 A0 = *reinterpret_cast<const bf16x8*>(
                &xbf[(rowb + m) * 72 + 8 * hi]);
#pragma unroll
            for (int kt = 0; kt < 4; ++kt)
                acc[kt] = __builtin_amdgcn_mfma_f32_16x16x32_bf16(
                    A0, Bf[kt][0], acc[kt], 0, 0, 0);
            const bf16x8 A1 = *reinterpret_cast<const bf16x8*>(
                &xbf[(rowb + m) * 72 + 32 + 8 * hi]);
#pragma unroll
            for (int kt = 0; kt < 4; ++kt)
                acc[kt] = __builtin_amdgcn_mfma_f32_16x16x32_bf16(
                    A1, Bf[kt][1], acc[kt], 0, 0, 0);
        }
        const float4 tr =
            *reinterpret_cast<const float4*>(&thr[rowb + 4 * hi]);
#pragma unroll
        for (int kt = 0; kt < 4; ++kt) {
            const int kg = 64 * w + kt * 16 + m;
            const float dd0 = fmaf(-2.f, acc[kt][0], se[kt]);
            const float dd1 = fmaf(-2.f, acc[kt][1], se[kt]);
            const float dd2 = fmaf(-2.f, acc[kt][2], se[kt]);
            const float dd3 = fmaf(-2.f, acc[kt][3], se[kt]);
            if (dd0 <= tr.x) {
                const unsigned idx = atomicAdd(&cnt[rowb + 4 * hi + 0], 1u);
                if (idx < CAP) list[(rowb + 4 * hi + 0) * CAP + idx] = (unsigned short)kg;
            }
            if (dd1 <= tr.y) {
                const unsigned idx = atomicAdd(&cnt[rowb + 4 * hi + 1], 1u);
                if (idx < CAP) list[(rowb + 4 * hi + 1) * CAP + idx] = (unsigned short)kg;
            }
            if (dd2 <= tr.z) {
                const unsigned idx = atomicAdd(&cnt[rowb + 4 * hi + 2], 1u);
                if (idx < CAP) list[(rowb + 4 * hi + 2) * CAP + idx] = (unsigned short)kg;
            }
            if (dd3 <= tr.w) {
                const unsigned idx = atomicAdd(&cnt[rowb + 4 * hi + 3], 1u);
                if (idx < CAP) list[(rowb + 4 * hi + 3) * CAP + idx] = (unsigned short)kg;
            }
        }
    }
    __syncthreads();  // bar4

    // ---- Exact rescore (bitwise numpy chain); 4 threads per pos ----
    {
        const int p = tid >> 2, sub = tid & 3;
        const unsigned n = cnt[p];
        const float sx = (sqxp[p] + sqxp[POSB + p]) +
                         (sqxp[2 * POSB + p] + sqxp[3 * POSB + p]);
        unsigned long long mloc = ~0ULL;
        if (n <= CAP) {
            for (unsigned c = sub; c < n; c += 4) {
                const int k = list[p * CAP + c];
                float M = 0.f;
#pragma unroll 8
                for (int d = 0; d < D; ++d)
                    M = fmaf(eb[(size_t)d * HW + p], cb[d * Kc + k], M);
                const float m2 = 2.0f * M;
                const float tmp = sx - m2;
                const float dd = tmp + sqe[k];
                const unsigned long long pk =
                    ((unsigned long long)__float_as_uint(dd) << 32) | (unsigned)k;
                if (pk < mloc) mloc = pk;
            }
        } else {  // overflow: full exact rescan (practically never; airtight)
            for (unsigned k = sub; k < (unsigned)Kc; k += 4) {
                float M = 0.f;
#pragma unroll 8
                for (int d = 0; d < D; ++d)
                    M = fmaf(eb[(size_t)d * HW + p], cb[d * Kc + k], M);
                const float m2 = 2.0f * M;
                const float tmp = sx - m2;
                const float dd = tmp + sqe[k];
                const unsigned long long pk =
                    ((unsigned long long)__float_as_uint(dd) << 32) | k;
                if (pk < mloc) mloc = pk;
            }
        }
        if (mloc != ~0ULL) atomicMin(&rmin[p], mloc);
    }
    __syncthreads();  // bar5

    // ---- Output: thread (d = tid>>3, pg = tid&7), 2 reps of 8 pos ----
    {
        const int d = tid >> 3, pg = tid & 7;
        float* ob = out + (size_t)b * (D * HW) + r0 + (size_t)d * HW;
#pragma unroll
        for (int r = 0; r < 2; ++r) {
            const int pb = r * 64 + pg * 8;
            float o[8];
#pragma unroll
            for (int i = 0; i < 8; ++i) {
                const int k = (int)(rmin[pb + i] & 0xffffffffu);
                o[i] = cb[d * Kc + k];
            }
            float4 v0 = {o[0], o[1], o[2], o[3]};
            float4 v1 = {o[4], o[5], o[6], o[7]};
            *reinterpret_cast<float4*>(ob + pb) = v0;
            *reinterpret_cast<float4*>(ob + pb + 4) = v1;
        }
    }
}

extern "C" void kernel_launch(void* const* d_in, const int* in_sizes, int n_in,
                              void* d_out, int out_size, void* d_ws, size_t ws_size,
                              hipStream_t stream) {
    const float* enc = (const float*)d_in[0];  // [32,64,64,64]
    const float* cb  = (const float*)d_in[1];  // [64,512]
    float* out = (float*)d_out;
    float* sqe = (float*)d_ws;                           // 512 f32
    float* maxsqe = (float*)((char*)d_ws + 2048);        // 1 f32
    unsigned short* cbT = (unsigned short*)((char*)d_ws + 4096);  // 64 KB

    vq_prep<<<1, 512, 0, stream>>>(cb, sqe, maxsqe, cbT);
    vq_mfma3<<<Np / POSB, 512, 0, stream>>>(enc, cb, sqe, maxsqe, cbT, out);
}